// Round 8
// baseline (357.020 us; speedup 1.0000x reference)
//
#include <hip/hip_runtime.h>
#include <hip/hip_cooperative_groups.h>

namespace cg = cooperative_groups;

#define NN 500000
#define QTR 125000
#define KK 3
#define EE (NN * KK)
#define HH 64
#define NC 8
#define NIN 16
#define EIN 8
#define TPB 256
#define NBLK 512   // 489 active; 2 blocks/CU co-residency needed (margin vs 4/CU max)

typedef __attribute__((ext_vector_type(2))) _Float16 h2;
typedef __attribute__((ext_vector_type(2)))  float sf2;
typedef __attribute__((ext_vector_type(8)))  float sf8;
typedef __attribute__((ext_vector_type(16))) float sf16;

using pk_t = decltype(__builtin_amdgcn_cvt_pkrtz(0.f, 0.f));

// Guaranteed-scalar loads of wave-uniform weight data (K$-cached, scalar pipe).
__device__ __forceinline__ sf2 sload2(const float* p) {
    sf2 r; asm("s_load_dwordx2 %0, %1, 0x0" : "=s"(r) : "s"(p)); return r;
}
__device__ __forceinline__ sf8 sload8(const float* p) {
    sf8 r; asm("s_load_dwordx8 %0, %1, 0x0" : "=s"(r) : "s"(p)); return r;
}
__device__ __forceinline__ sf16 sload16(const float* p) {
    sf16 r; asm("s_load_dwordx16 %0, %1, 0x0" : "=s"(r) : "s"(p)); return r;
}
#define SWAIT1(a)         asm volatile("s_waitcnt lgkmcnt(0)" : "+s"(a))
#define SWAIT2(a,b)       asm volatile("s_waitcnt lgkmcnt(0)" : "+s"(a),"+s"(b))
#define SWAIT3(a,b,c)     asm volatile("s_waitcnt lgkmcnt(0)" : "+s"(a),"+s"(b),"+s"(c))
#define SWAIT4(a,b,c,d)   asm volatile("s_waitcnt lgkmcnt(0)" : "+s"(a),"+s"(b),"+s"(c),"+s"(d))
#define SWAIT5(a,b,c,d,e) asm volatile("s_waitcnt lgkmcnt(0)" : "+s"(a),"+s"(b),"+s"(c),"+s"(d),"+s"(e))

#if __has_builtin(__builtin_elementwise_fma)
#define PKFMA(a,b,c) __builtin_elementwise_fma((a),(b),(c))
#else
#define PKFMA(a,b,c) ((a)*(b)+(c))
#endif

__device__ __forceinline__ h2 bch2(float f)        { return __builtin_bit_cast(h2, f); }
__device__ __forceinline__ h2 bch2u(unsigned int u){ return __builtin_bit_cast(h2, u); }
__device__ __forceinline__ h2 dup16(float f) {
    return __builtin_bit_cast(h2, __builtin_amdgcn_cvt_pkrtz(f, f));
}
__device__ __forceinline__ unsigned int pkrtz_u(float a, float b) {
    return __builtin_bit_cast(unsigned int, __builtin_amdgcn_cvt_pkrtz(a, b));
}
__device__ __forceinline__ h2 splat_lo(unsigned int u) {
    h2 p = bch2u(u); h2 r; r.x = p.x; r.y = p.x; return r;
}
__device__ __forceinline__ h2 splat_hi(unsigned int u) {
    h2 p = bch2u(u); h2 r; r.x = p.y; r.y = p.y; return r;
}
__device__ __forceinline__ float lo_f32(unsigned int u) { return (float)bch2u(u).x; }
__device__ __forceinline__ float hi_f32(unsigned int u) { return (float)bch2u(u).y; }

__device__ __forceinline__ float fdot2(h2 a, h2 b, float c) {
#if __has_builtin(__builtin_amdgcn_fdot2)
    return __builtin_amdgcn_fdot2(__builtin_bit_cast(pk_t, a),
                                  __builtin_bit_cast(pk_t, b), c, false);
#else
    return c + (float)a.x * (float)b.x + (float)a.y * (float)b.y;
#endif
}
__device__ __forceinline__ h2 lk2(h2 x) {
    h2 c = {(_Float16)0.1f, (_Float16)0.1f};
    return __builtin_elementwise_max(x, x * c);
}
__device__ __forceinline__ float pack2(float a, float b) {
    h2 v; v.x = (_Float16)a; v.y = (_Float16)b;
    return __builtin_bit_cast(float, v);
}

struct KParams {
    const float* node_feat; const float* edge_attr; const int* nbr;
    const float* Wn; const float* bn; const float* We; const float* be;
    const float* msgW1; const float* msgb1; const float* msgW2; const float* msgb2;
    const float* updW1; const float* updb1; const float* updW2; const float* updb2;
    const float* finW1; const float* finb1; const float* finW2; const float* finb2;
    unsigned int* hbufA; unsigned int* hbufB; float* wpack; float* out;
};

__device__ __forceinline__ unsigned int proj_node(const float* node_feat, int idx,
                                                  const sf16& wn0, const sf16& wn1,
                                                  const sf2& bnv) {
    const float4* x4 = (const float4*)(node_feat + (size_t)idx * NIN);
    float4 v0 = x4[0], v1 = x4[1], v2 = x4[2], v3 = x4[3];
    float xs[16] = {v0.x, v0.y, v0.z, v0.w, v1.x, v1.y, v1.z, v1.w,
                    v2.x, v2.y, v2.z, v2.w, v3.x, v3.y, v3.z, v3.w};
    float a0 = bnv.x, a1 = bnv.y;
#pragma unroll
    for (int i = 0; i < 8; i++) {
        a0 = fmaf(xs[i], wn0[2 * i], a0);
        a1 = fmaf(xs[i], wn0[2 * i + 1], a1);
    }
#pragma unroll
    for (int i = 0; i < 8; i++) {
        a0 = fmaf(xs[8 + i], wn1[2 * i], a0);
        a1 = fmaf(xs[8 + i], wn1[2 * i + 1], a1);
    }
    return pkrtz_u(a0, a1);
}

__device__ __forceinline__ unsigned int proj_edge(const float* edge_attr, int eidx,
                                                  const sf16& wev, const sf2& bev) {
    const float4* x4 = (const float4*)(edge_attr + (size_t)eidx * EIN);
    float4 v0 = x4[0], v1 = x4[1];
    float xs[8] = {v0.x, v0.y, v0.z, v0.w, v1.x, v1.y, v1.z, v1.w};
    float a0 = bev.x, a1 = bev.y;
#pragma unroll
    for (int i = 0; i < 8; i++) {
        a0 = fmaf(xs[i], wev[2 * i], a0);
        a1 = fmaf(xs[i], wev[2 * i + 1], a1);
    }
    return pkrtz_u(a0, a1);
}

// One GNN layer on 4 register-resident nodes. Weights streamed via SGPRs.
template<bool FINAL>
__device__ __forceinline__ void layer_phase(
    const KParams& P, int l, const int* idx,
    const unsigned int* h, const int* nb, const unsigned int* ee,
    const unsigned int* __restrict__ hp_in, unsigned int* nh)
{
    const float* mblk = P.wpack + (2 * l) * 256;
    const float* ublk = P.wpack + (2 * l + 1) * 256;
    sf2 mb2v = sload2(P.msgb2 + 2 * l);
    sf2 ub2v = sload2(P.updb2 + 2 * l);
    SWAIT2(mb2v, ub2v);

    // gather neighbor h (12 x u32) and splat everything once
    h2 ex[12], ey[12], gx[12], gy[12];
#pragma unroll
    for (int k = 0; k < 12; k++) {
        unsigned int g = hp_in[nb[k]];
        ex[k] = splat_lo(ee[k]); ey[k] = splat_hi(ee[k]);
        gx[k] = splat_lo(g);     gy[k] = splat_hi(g);
    }

    // aggr = (sum_e leaky([e,hn]@W1+b1)) @ W2 + 3*b2
    float a0[4], a1[4];
#pragma unroll
    for (int n = 0; n < 4; n++) { a0[n] = 3.0f * mb2v.x; a1[n] = 3.0f * mb2v.y; }
#pragma unroll 1
    for (int c = 0; c < 8; c += 2) {
        sf16 A0 = sload16(mblk + c * 32);
        sf16 B0 = sload16(mblk + c * 32 + 16);
        sf16 A1 = sload16(mblk + c * 32 + 32);
        sf16 B1 = sload16(mblk + c * 32 + 48);
        SWAIT4(A0, B0, A1, B1);
#pragma unroll
        for (int half = 0; half < 2; half++) {
            const sf16& A = half ? A1 : A0;
            const sf16& B = half ? B1 : B0;
#pragma unroll
            for (int jp = 0; jp < 4; jp++) {
                h2 w0 = bch2(A[jp]), w1 = bch2(A[4 + jp]);
                h2 w2 = bch2(A[8 + jp]), w3 = bch2(A[12 + jp]);
                h2 bb = bch2(B[jp]);
                h2 wcx = bch2(B[4 + jp]), wcy = bch2(B[8 + jp]);
#pragma unroll
                for (int n = 0; n < 4; n++) {
                    int k = 3 * n;
                    h2 t0 = PKFMA(ex[k],     w0, PKFMA(ey[k],     w1, PKFMA(gx[k],     w2, PKFMA(gy[k],     w3, bb))));
                    h2 t1 = PKFMA(ex[k + 1], w0, PKFMA(ey[k + 1], w1, PKFMA(gx[k + 1], w2, PKFMA(gy[k + 1], w3, bb))));
                    h2 t2 = PKFMA(ex[k + 2], w0, PKFMA(ey[k + 2], w1, PKFMA(gx[k + 2], w2, PKFMA(gy[k + 2], w3, bb))));
                    h2 ts = lk2(t0) + lk2(t1) + lk2(t2);
                    a0[n] = fdot2(ts, wcx, a0[n]);
                    a1[n] = fdot2(ts, wcy, a1[n]);
                }
            }
        }
    }

    // update MLP on concat(h, aggr)
    h2 hx[4], hy[4], ax[4], ay[4];
#pragma unroll
    for (int n = 0; n < 4; n++) {
        hx[n] = splat_lo(h[n]); hy[n] = splat_hi(h[n]);
        ax[n] = dup16(a0[n]);   ay[n] = dup16(a1[n]);
    }
    float u0[4], u1[4];
#pragma unroll
    for (int n = 0; n < 4; n++) { u0[n] = ub2v.x; u1[n] = ub2v.y; }
#pragma unroll 1
    for (int c = 0; c < 8; c += 2) {
        sf16 A0 = sload16(ublk + c * 32);
        sf16 B0 = sload16(ublk + c * 32 + 16);
        sf16 A1 = sload16(ublk + c * 32 + 32);
        sf16 B1 = sload16(ublk + c * 32 + 48);
        SWAIT4(A0, B0, A1, B1);
#pragma unroll
        for (int half = 0; half < 2; half++) {
            const sf16& A = half ? A1 : A0;
            const sf16& B = half ? B1 : B0;
#pragma unroll
            for (int jp = 0; jp < 4; jp++) {
                h2 w0 = bch2(A[jp]), w1 = bch2(A[4 + jp]);
                h2 w2 = bch2(A[8 + jp]), w3 = bch2(A[12 + jp]);
                h2 bb = bch2(B[jp]);
                h2 wcx = bch2(B[4 + jp]), wcy = bch2(B[8 + jp]);
#pragma unroll
                for (int n = 0; n < 4; n++) {
                    h2 tt = PKFMA(hx[n], w0, PKFMA(hy[n], w1, PKFMA(ax[n], w2, PKFMA(ay[n], w3, bb))));
                    tt = lk2(tt);
                    u0[n] = fdot2(tt, wcx, u0[n]);
                    u1[n] = fdot2(tt, wcy, u1[n]);
                }
            }
        }
    }
    float nh0[4], nh1[4];
#pragma unroll
    for (int n = 0; n < 4; n++) {
        nh0[n] = fmaxf(lo_f32(h[n]) + u0[n], 0.0f);
        nh1[n] = fmaxf(hi_f32(h[n]) + u1[n], 0.0f);
        nh[n] = pkrtz_u(nh0[n], nh1[n]);
    }

    if constexpr (FINAL) {
        const float* fblk = P.wpack + 1024;
        sf8 fb2v = sload8(P.finb2);
        SWAIT1(fb2v);
        float o[4][NC];
#pragma unroll
        for (int n = 0; n < 4; n++)
#pragma unroll
            for (int cc = 0; cc < NC; cc++) o[n][cc] = fb2v[cc];
        h2 nx[4], ny[4];
#pragma unroll
        for (int n = 0; n < 4; n++) { nx[n] = dup16(nh0[n]); ny[n] = dup16(nh1[n]); }
#pragma unroll 1
        for (int c = 0; c < 8; c++) {
            sf16 A = sload16(fblk + c * 48);
            sf16 B = sload16(fblk + c * 48 + 16);
            sf16 C = sload16(fblk + c * 48 + 32);
            SWAIT3(A, B, C);
#pragma unroll
            for (int jp = 0; jp < 4; jp++) {
                h2 w1a = bch2(A[jp]), w1b = bch2(A[4 + jp]), bb = bch2(A[8 + jp]);
                h2 tt[4];
#pragma unroll
                for (int n = 0; n < 4; n++)
                    tt[n] = lk2(PKFMA(nx[n], w1a, PKFMA(ny[n], w1b, bb)));
#pragma unroll
                for (int cc = 0; cc < NC; cc++) {
                    float w = (jp < 2) ? B[(jp & 1) * 8 + cc] : C[(jp & 1) * 8 + cc];
                    h2 wv = bch2(w);
#pragma unroll
                    for (int n = 0; n < 4; n++) o[n][cc] = fdot2(tt[n], wv, o[n][cc]);
                }
            }
        }
#pragma unroll
        for (int n = 0; n < 4; n++) {
            float4* op = (float4*)(P.out + (size_t)idx[n] * NC);
            op[0] = make_float4(o[n][0], o[n][1], o[n][2], o[n][3]);
            op[1] = make_float4(o[n][4], o[n][5], o[n][6], o[n][7]);
        }
    }
}

__global__ __launch_bounds__(TPB, 2) void fused_kernel(KParams P) {
    cg::grid_group grid = cg::this_grid();
    const int t = blockIdx.x * TPB + threadIdx.x;
    const bool active = (t < QTR);
    int idx[4];
#pragma unroll
    for (int n = 0; n < 4; n++) idx[n] = t + n * QTR;

    // ---- weight pack (block 0 only; visible grid-wide after grid.sync) ----
    if (blockIdx.x == 0) {
        int tt = threadIdx.x;
        if (tt < 32) {
            int l = tt >> 4, which = (tt >> 3) & 1, c = tt & 7;
            const float* W1 = (which ? P.updW1 : P.msgW1) + l * 4 * HH;
            const float* b1 = (which ? P.updb1 : P.msgb1) + l * HH;
            const float* W2 = (which ? P.updW2 : P.msgW2) + l * 2 * HH;
            float* dst = P.wpack + (l * 2 + which) * 256 + c * 32;
            int j0 = c * 8;
            for (int r = 0; r < 4; r++)
                for (int p = 0; p < 4; p++)
                    dst[r * 4 + p] = pack2(W1[r * HH + j0 + 2 * p], W1[r * HH + j0 + 2 * p + 1]);
            for (int p = 0; p < 4; p++) {
                dst[16 + p] = pack2(b1[j0 + 2 * p], b1[j0 + 2 * p + 1]);
                dst[20 + p] = pack2(W2[(j0 + 2 * p) * 2 + 0], W2[(j0 + 2 * p + 1) * 2 + 0]);
                dst[24 + p] = pack2(W2[(j0 + 2 * p) * 2 + 1], W2[(j0 + 2 * p + 1) * 2 + 1]);
                dst[28 + p] = 0.0f;
            }
        } else if (tt < 40) {
            int c = tt - 32, j0 = c * 8;
            float* dst = P.wpack + 1024 + c * 48;
            for (int p = 0; p < 4; p++) {
                dst[p]      = pack2(P.finW1[j0 + 2 * p],      P.finW1[j0 + 2 * p + 1]);
                dst[4 + p]  = pack2(P.finW1[HH + j0 + 2 * p], P.finW1[HH + j0 + 2 * p + 1]);
                dst[8 + p]  = pack2(P.finb1[j0 + 2 * p],      P.finb1[j0 + 2 * p + 1]);
                dst[12 + p] = 0.0f;
            }
            for (int jp = 0; jp < 4; jp++)
                for (int cc = 0; cc < NC; cc++)
                    dst[16 + jp * 8 + cc] = pack2(P.finW2[(j0 + 2 * jp) * NC + cc],
                                                  P.finW2[(j0 + 2 * jp + 1) * NC + cc]);
        }
    }

    // ---- phase A: input projections; edges + nbr stay in registers ----
    unsigned int h[4] = {0, 0, 0, 0};
    unsigned int ee[12] = {0};
    int nb[12] = {0};
    if (active) {
        sf16 wn0 = sload16(P.Wn);
        sf16 wn1 = sload16(P.Wn + 16);
        sf2  bnv = sload2(P.bn);
        sf16 wev = sload16(P.We);
        sf2  bev = sload2(P.be);
        SWAIT5(wn0, wn1, bnv, wev, bev);
#pragma unroll
        for (int n = 0; n < 4; n++) {
            h[n] = proj_node(P.node_feat, idx[n], wn0, wn1, bnv);
            P.hbufA[idx[n]] = h[n];
#pragma unroll
            for (int k = 0; k < 3; k++) {
                ee[3 * n + k] = proj_edge(P.edge_attr, idx[n] * KK + k, wev, bev);
                nb[3 * n + k] = P.nbr[idx[n] * KK + k];
            }
        }
    }
    grid.sync();

    // ---- phase B: layer 0 (read hbufA, write hbufB) ----
    unsigned int nh[4] = {0, 0, 0, 0};
    if (active) {
        layer_phase<false>(P, 0, idx, h, nb, ee, P.hbufA, nh);
#pragma unroll
        for (int n = 0; n < 4; n++) P.hbufB[idx[n]] = nh[n];
    }
    grid.sync();

    // ---- phase C: layer 1 + fused final MLP (read hbufB, write out) ----
    if (active) {
        unsigned int dd[4];
        layer_phase<true>(P, 1, idx, nh, nb, ee, P.hbufB, dd);
    }
}

extern "C" void kernel_launch(void* const* d_in, const int* in_sizes, int n_in,
                              void* d_out, int out_size, void* d_ws, size_t ws_size,
                              hipStream_t stream) {
    KParams P;
    P.node_feat = (const float*)d_in[0];
    P.edge_attr = (const float*)d_in[1];
    P.nbr = ((const int*)d_in[2]) + EE;   // edge_index[1] row
    // d_in[3] = batch (unused)
    P.Wn = (const float*)d_in[4];  P.bn = (const float*)d_in[5];
    P.We = (const float*)d_in[6];  P.be = (const float*)d_in[7];
    P.msgW1 = (const float*)d_in[8];  P.msgb1 = (const float*)d_in[9];
    P.msgW2 = (const float*)d_in[10]; P.msgb2 = (const float*)d_in[11];
    P.updW1 = (const float*)d_in[12]; P.updb1 = (const float*)d_in[13];
    P.updW2 = (const float*)d_in[14]; P.updb2 = (const float*)d_in[15];
    P.finW1 = (const float*)d_in[16]; P.finb1 = (const float*)d_in[17];
    P.finW2 = (const float*)d_in[18]; P.finb2 = (const float*)d_in[19];
    P.out = (float*)d_out;

    char* ws = (char*)d_ws;
    P.hbufA = (unsigned int*)ws;                      // NN u32 (2 MB)
    P.hbufB = (unsigned int*)(ws + (size_t)NN * 4);   // NN u32 (2 MB)
    P.wpack = (float*)(ws + (size_t)NN * 8);          // ~5.6 KB

    void* args[] = { (void*)&P };
    hipLaunchCooperativeKernel((const void*)fused_kernel,
                               dim3(NBLK), dim3(TPB), args, 0, stream);
}

// Round 9
// 197.355 us; speedup vs baseline: 1.8090x; 1.8090x over previous
//
#include <hip/hip_runtime.h>

#define NN 500000
#define KK 3
#define EE (NN * KK)
#define HH 64
#define NC 8
#define NIN 16
#define EIN 8

typedef __attribute__((ext_vector_type(2))) _Float16 h2;
typedef __attribute__((ext_vector_type(2)))  float sf2;
typedef __attribute__((ext_vector_type(8)))  float sf8;
typedef __attribute__((ext_vector_type(16))) float sf16;

using pk_t = decltype(__builtin_amdgcn_cvt_pkrtz(0.f, 0.f));

// Guaranteed-scalar loads of wave-uniform weight data (K$-cached, scalar pipe).
__device__ __forceinline__ sf2 sload2(const float* p) {
    sf2 r; asm("s_load_dwordx2 %0, %1, 0x0" : "=s"(r) : "s"(p)); return r;
}
__device__ __forceinline__ sf8 sload8(const float* p) {
    sf8 r; asm("s_load_dwordx8 %0, %1, 0x0" : "=s"(r) : "s"(p)); return r;
}
__device__ __forceinline__ sf16 sload16(const float* p) {
    sf16 r; asm("s_load_dwordx16 %0, %1, 0x0" : "=s"(r) : "s"(p)); return r;
}
#define SWAIT1(a)         asm volatile("s_waitcnt lgkmcnt(0)" : "+s"(a))
#define SWAIT2(a,b)       asm volatile("s_waitcnt lgkmcnt(0)" : "+s"(a),"+s"(b))
#define SWAIT3(a,b,c)     asm volatile("s_waitcnt lgkmcnt(0)" : "+s"(a),"+s"(b),"+s"(c))
#define SWAIT4(a,b,c,d)   asm volatile("s_waitcnt lgkmcnt(0)" : "+s"(a),"+s"(b),"+s"(c),"+s"(d))
#define SWAIT5(a,b,c,d,e) asm volatile("s_waitcnt lgkmcnt(0)" : "+s"(a),"+s"(b),"+s"(c),"+s"(d),"+s"(e))

#if __has_builtin(__builtin_elementwise_fma)
#define PKFMA(a,b,c) __builtin_elementwise_fma((a),(b),(c))
#else
#define PKFMA(a,b,c) ((a)*(b)+(c))
#endif

__device__ __forceinline__ h2 bch2(float f)        { return __builtin_bit_cast(h2, f); }
__device__ __forceinline__ h2 bch2u(unsigned int u){ return __builtin_bit_cast(h2, u); }
__device__ __forceinline__ h2 dup16(float f) {
    return __builtin_bit_cast(h2, __builtin_amdgcn_cvt_pkrtz(f, f));
}
__device__ __forceinline__ unsigned int pkrtz_u(float a, float b) {
    return __builtin_bit_cast(unsigned int, __builtin_amdgcn_cvt_pkrtz(a, b));
}
__device__ __forceinline__ h2 splat_lo(unsigned int u) {
    h2 p = bch2u(u); h2 r; r.x = p.x; r.y = p.x; return r;
}
__device__ __forceinline__ h2 splat_hi(unsigned int u) {
    h2 p = bch2u(u); h2 r; r.x = p.y; r.y = p.y; return r;
}
__device__ __forceinline__ float lo_f32(unsigned int u) { return (float)bch2u(u).x; }
__device__ __forceinline__ float hi_f32(unsigned int u) { return (float)bch2u(u).y; }

__device__ __forceinline__ float fdot2(h2 a, h2 b, float c) {
#if __has_builtin(__builtin_amdgcn_fdot2)
    return __builtin_amdgcn_fdot2(__builtin_bit_cast(pk_t, a),
                                  __builtin_bit_cast(pk_t, b), c, false);
#else
    return c + (float)a.x * (float)b.x + (float)a.y * (float)b.y;
#endif
}
__device__ __forceinline__ h2 lk2(h2 x) {
    h2 c = {(_Float16)0.1f, (_Float16)0.1f};
    return __builtin_elementwise_max(x, x * c);
}
__device__ __forceinline__ float pack2(float a, float b) {
    h2 v; v.x = (_Float16)a; v.y = (_Float16)b;   // RTN conversion for weights
    return __builtin_bit_cast(float, v);
}

// ---- fused input projections (packed u32 outputs) + inline weight packing ----
// wpack layout: msg/upd block (l*2+which)*256 dwords, 8 chunks x 32 dwords:
//   [0:3]=W1row0 pairs, [4:7]=row1, [8:11]=row2, [12:15]=row3,
//   [16:19]=b1 pairs, [20:23]=W2[:,0] pairs, [24:27]=W2[:,1] pairs, [28:31]=pad
// final block at 1024: 8 chunks x 48 dwords:
//   [0:3]=fW1row0 pairs, [4:7]=row1, [8:11]=fb1 pairs, [12:15]=pad,
//   [16+jp*8+c] = pack(fW2[j0+2jp][c], fW2[j0+2jp+1][c])
__global__ __launch_bounds__(256) void prep_kernel(
    const float* __restrict__ node_feat, const float* __restrict__ edge_attr,
    const float* __restrict__ Wn, const float* __restrict__ bn,
    const float* __restrict__ We, const float* __restrict__ be,
    unsigned int* __restrict__ hp, unsigned int* __restrict__ ep,
    const float* __restrict__ msgW1, const float* __restrict__ msgb1, const float* __restrict__ msgW2,
    const float* __restrict__ updW1, const float* __restrict__ updb1, const float* __restrict__ updW2,
    const float* __restrict__ finW1, const float* __restrict__ finb1, const float* __restrict__ finW2,
    float* __restrict__ wpack)
{
    sf16 wn0 = sload16(Wn);
    sf16 wn1 = sload16(Wn + 16);
    sf2  bnv = sload2(bn);
    sf16 wev = sload16(We);
    sf2  bev = sload2(be);
    SWAIT5(wn0, wn1, bnv, wev, bev);

    int idx = blockIdx.x * 256 + threadIdx.x;
    if (idx < NN) {
        const float4* x4 = (const float4*)(node_feat + (size_t)idx * NIN);
        float4 v0 = x4[0], v1 = x4[1], v2 = x4[2], v3 = x4[3];
        float xs[16] = {v0.x, v0.y, v0.z, v0.w, v1.x, v1.y, v1.z, v1.w,
                        v2.x, v2.y, v2.z, v2.w, v3.x, v3.y, v3.z, v3.w};
        float a0 = bnv.x, a1 = bnv.y;
#pragma unroll
        for (int i = 0; i < 8; i++) {
            a0 = fmaf(xs[i], wn0[2 * i], a0);
            a1 = fmaf(xs[i], wn0[2 * i + 1], a1);
        }
#pragma unroll
        for (int i = 0; i < 8; i++) {
            a0 = fmaf(xs[8 + i], wn1[2 * i], a0);
            a1 = fmaf(xs[8 + i], wn1[2 * i + 1], a1);
        }
        hp[idx] = pkrtz_u(a0, a1);
    } else if (idx < NN + EE) {
        int eidx = idx - NN;
        const float4* x4 = (const float4*)(edge_attr + (size_t)eidx * EIN);
        float4 v0 = x4[0], v1 = x4[1];
        float xs[8] = {v0.x, v0.y, v0.z, v0.w, v1.x, v1.y, v1.z, v1.w};
        float a0 = bev.x, a1 = bev.y;
#pragma unroll
        for (int i = 0; i < 8; i++) {
            a0 = fmaf(xs[i], wev[2 * i], a0);
            a1 = fmaf(xs[i], wev[2 * i + 1], a1);
        }
        ep[eidx] = pkrtz_u(a0, a1);
    }

    // ---- inline weight packing (block 0 only; tiny serial side-work) ----
    if (blockIdx.x == 0) {
        int t = threadIdx.x;
        if (t < 32) {
            int l = t >> 4, which = (t >> 3) & 1, c = t & 7;
            const float* W1 = (which ? updW1 : msgW1) + l * 4 * HH;
            const float* b1 = (which ? updb1 : msgb1) + l * HH;
            const float* W2 = (which ? updW2 : msgW2) + l * 2 * HH;
            float* dst = wpack + (l * 2 + which) * 256 + c * 32;
            int j0 = c * 8;
            for (int r = 0; r < 4; r++)
                for (int p = 0; p < 4; p++)
                    dst[r * 4 + p] = pack2(W1[r * HH + j0 + 2 * p], W1[r * HH + j0 + 2 * p + 1]);
            for (int p = 0; p < 4; p++) {
                dst[16 + p] = pack2(b1[j0 + 2 * p], b1[j0 + 2 * p + 1]);
                dst[20 + p] = pack2(W2[(j0 + 2 * p) * 2 + 0], W2[(j0 + 2 * p + 1) * 2 + 0]);
                dst[24 + p] = pack2(W2[(j0 + 2 * p) * 2 + 1], W2[(j0 + 2 * p + 1) * 2 + 1]);
                dst[28 + p] = 0.0f;
            }
        } else if (t < 40) {
            int c = t - 32, j0 = c * 8;
            float* dst = wpack + 1024 + c * 48;
            for (int p = 0; p < 4; p++) {
                dst[p]      = pack2(finW1[j0 + 2 * p],      finW1[j0 + 2 * p + 1]);
                dst[4 + p]  = pack2(finW1[HH + j0 + 2 * p], finW1[HH + j0 + 2 * p + 1]);
                dst[8 + p]  = pack2(finb1[j0 + 2 * p],      finb1[j0 + 2 * p + 1]);
                dst[12 + p] = 0.0f;
            }
            for (int jp = 0; jp < 4; jp++)
                for (int cc = 0; cc < NC; cc++)
                    dst[16 + jp * 8 + cc] = pack2(finW2[(j0 + 2 * jp) * NC + cc],
                                                  finW2[(j0 + 2 * jp + 1) * NC + cc]);
        }
    }
}

// ---- one GNN layer; 1 node/thread (max waves), packed-f16 VALU, f32 accum ----
template<bool FINAL>
__global__ __launch_bounds__(256) void layer_kernel(
    const unsigned int* __restrict__ hp_in, const unsigned int* __restrict__ eP,
    const int* __restrict__ nbr,
    const float* __restrict__ mblk, const float* __restrict__ mb2,
    const float* __restrict__ ublk, const float* __restrict__ ub2,
    unsigned int* __restrict__ hp_out,
    const float* __restrict__ fblk, const float* __restrict__ fb2,
    float* __restrict__ out)
{
    int i = blockIdx.x * 256 + threadIdx.x;
    if (i >= NN) return;

    sf2 mb2v = sload2(mb2);
    sf2 ub2v = sload2(ub2);
    SWAIT2(mb2v, ub2v);

    unsigned int hO = hp_in[i];
    int base = i * KK;
    int n0 = nbr[base + 0], n1 = nbr[base + 1], n2 = nbr[base + 2];
    unsigned int g0 = hp_in[n0], g1 = hp_in[n1], g2 = hp_in[n2];
    unsigned int e0 = eP[base + 0], e1 = eP[base + 1], e2 = eP[base + 2];

    h2 e0x = splat_lo(e0), e0y = splat_hi(e0);
    h2 e1x = splat_lo(e1), e1y = splat_hi(e1);
    h2 e2x = splat_lo(e2), e2y = splat_hi(e2);
    h2 n0x = splat_lo(g0), n0y = splat_hi(g0);
    h2 n1x = splat_lo(g1), n1y = splat_hi(g1);
    h2 n2x = splat_lo(g2), n2y = splat_hi(g2);

    // aggr = (sum_e leaky([e,hn]@W1+b1)) @ W2 + 3*b2  (linearity of segment_sum)
    float a0 = 3.0f * mb2v.x, a1 = 3.0f * mb2v.y;
#pragma unroll 1
    for (int c = 0; c < 8; c += 2) {
        sf16 A0 = sload16(mblk + c * 32);
        sf16 B0 = sload16(mblk + c * 32 + 16);
        sf16 A1 = sload16(mblk + c * 32 + 32);
        sf16 B1 = sload16(mblk + c * 32 + 48);
        SWAIT4(A0, B0, A1, B1);
#pragma unroll
        for (int half = 0; half < 2; half++) {
            const sf16& A = half ? A1 : A0;
            const sf16& B = half ? B1 : B0;
#pragma unroll
            for (int jp = 0; jp < 4; jp++) {
                h2 w0 = bch2(A[jp]), w1 = bch2(A[4 + jp]);
                h2 w2 = bch2(A[8 + jp]), w3 = bch2(A[12 + jp]);
                h2 bb = bch2(B[jp]);
                h2 t0 = PKFMA(e0x, w0, PKFMA(e0y, w1, PKFMA(n0x, w2, PKFMA(n0y, w3, bb))));
                h2 t1 = PKFMA(e1x, w0, PKFMA(e1y, w1, PKFMA(n1x, w2, PKFMA(n1y, w3, bb))));
                h2 t2 = PKFMA(e2x, w0, PKFMA(e2y, w1, PKFMA(n2x, w2, PKFMA(n2y, w3, bb))));
                h2 ts = lk2(t0) + lk2(t1) + lk2(t2);
                a0 = fdot2(ts, bch2(B[4 + jp]), a0);
                a1 = fdot2(ts, bch2(B[8 + jp]), a1);
            }
        }
    }

    // update MLP on concat(h, aggr)
    h2 hx = splat_lo(hO), hy = splat_hi(hO);
    h2 ax = dup16(a0), ay = dup16(a1);
    float u0 = ub2v.x, u1 = ub2v.y;
#pragma unroll 1
    for (int c = 0; c < 8; c += 2) {
        sf16 A0 = sload16(ublk + c * 32);
        sf16 B0 = sload16(ublk + c * 32 + 16);
        sf16 A1 = sload16(ublk + c * 32 + 32);
        sf16 B1 = sload16(ublk + c * 32 + 48);
        SWAIT4(A0, B0, A1, B1);
#pragma unroll
        for (int half = 0; half < 2; half++) {
            const sf16& A = half ? A1 : A0;
            const sf16& B = half ? B1 : B0;
#pragma unroll
            for (int jp = 0; jp < 4; jp++) {
                h2 tt = PKFMA(hx, bch2(A[jp]),
                        PKFMA(hy, bch2(A[4 + jp]),
                        PKFMA(ax, bch2(A[8 + jp]),
                        PKFMA(ay, bch2(A[12 + jp]), bch2(B[jp])))));
                tt = lk2(tt);
                u0 = fdot2(tt, bch2(B[4 + jp]), u0);
                u1 = fdot2(tt, bch2(B[8 + jp]), u1);
            }
        }
    }
    float nh0 = fmaxf(lo_f32(hO) + u0, 0.0f);
    float nh1 = fmaxf(hi_f32(hO) + u1, 0.0f);

    if constexpr (!FINAL) {
        hp_out[i] = pkrtz_u(nh0, nh1);
    } else {
        sf8 fb2v = sload8(fb2);
        SWAIT1(fb2v);
        float o[NC];
#pragma unroll
        for (int cc = 0; cc < NC; cc++) o[cc] = fb2v[cc];
        h2 nx = dup16(nh0), ny = dup16(nh1);
#pragma unroll 1
        for (int c = 0; c < 8; c++) {
            sf16 A = sload16(fblk + c * 48);
            sf16 B = sload16(fblk + c * 48 + 16);
            sf16 C = sload16(fblk + c * 48 + 32);
            SWAIT3(A, B, C);
#pragma unroll
            for (int jp = 0; jp < 4; jp++) {
                h2 w1a = bch2(A[jp]), w1b = bch2(A[4 + jp]), bb = bch2(A[8 + jp]);
                h2 tt = lk2(PKFMA(nx, w1a, PKFMA(ny, w1b, bb)));
#pragma unroll
                for (int cc = 0; cc < NC; cc++) {
                    float w = (jp < 2) ? B[(jp & 1) * 8 + cc] : C[(jp & 1) * 8 + cc];
                    o[cc] = fdot2(tt, bch2(w), o[cc]);
                }
            }
        }
        float4* op = (float4*)(out + (size_t)i * NC);
        op[0] = make_float4(o[0], o[1], o[2], o[3]);
        op[1] = make_float4(o[4], o[5], o[6], o[7]);
    }
}

extern "C" void kernel_launch(void* const* d_in, const int* in_sizes, int n_in,
                              void* d_out, int out_size, void* d_ws, size_t ws_size,
                              hipStream_t stream) {
    const float* node_feat = (const float*)d_in[0];
    const float* edge_attr = (const float*)d_in[1];
    const int* edge_index = (const int*)d_in[2];
    // d_in[3] = batch (unused)
    const float* Wn = (const float*)d_in[4];
    const float* bn = (const float*)d_in[5];
    const float* We = (const float*)d_in[6];
    const float* be = (const float*)d_in[7];
    const float* msgW1 = (const float*)d_in[8];
    const float* msgb1 = (const float*)d_in[9];
    const float* msgW2 = (const float*)d_in[10];
    const float* msgb2 = (const float*)d_in[11];
    const float* updW1 = (const float*)d_in[12];
    const float* updb1 = (const float*)d_in[13];
    const float* updW2 = (const float*)d_in[14];
    const float* updb2 = (const float*)d_in[15];
    const float* finW1 = (const float*)d_in[16];
    const float* finb1 = (const float*)d_in[17];
    const float* finW2 = (const float*)d_in[18];
    const float* finb2 = (const float*)d_in[19];
    float* out = (float*)d_out;

    const int* nbr = edge_index + EE;  // edge_index[1] row

    char* ws = (char*)d_ws;
    unsigned int* hA = (unsigned int*)ws;                         // NN u32 (2 MB)
    unsigned int* hB = (unsigned int*)(ws + (size_t)NN * 4);      // NN u32 (2 MB)
    unsigned int* eP = (unsigned int*)(ws + (size_t)NN * 8);      // EE u32 (6 MB)
    float* wpack = (float*)(ws + (size_t)NN * 8 + (size_t)EE * 4);// ~5.6 KB

    const int threads = 256;
    int prep_grid = (NN + EE + threads - 1) / threads;
    prep_kernel<<<prep_grid, threads, 0, stream>>>(
        node_feat, edge_attr, Wn, bn, We, be, hA, eP,
        msgW1, msgb1, msgW2, updW1, updb1, updW2,
        finW1, finb1, finW2, wpack);

    int grid = (NN + threads - 1) / threads;   // 1 node/thread -> ~7816 waves (95% of slots)
    // wpack blocks: (l*2 + which)*256 dwords; final at 1024
    layer_kernel<false><<<grid, threads, 0, stream>>>(
        hA, eP, nbr,
        wpack + 0 * 256, msgb2,
        wpack + 1 * 256, updb2,
        hB, wpack + 1024, finb2, nullptr);
    layer_kernel<true><<<grid, threads, 0, stream>>>(
        hB, eP, nbr,
        wpack + 2 * 256, msgb2 + 2,
        wpack + 3 * 256, updb2 + 2,
        nullptr, wpack + 1024, finb2, out);
}